// Round 2
// baseline (670.740 us; speedup 1.0000x reference)
//
#include <hip/hip_runtime.h>

// GPT-2 block forward, MI355X/gfx950. B=4 T=2048 C=768 H=12 D=64; M=8192.
// Runtime dtype detection: inputs may be fp32 or bf16 (flag in ws).
// Internally everything runs bf16 (fp32 accum), residual stream x1 in fp32.

typedef unsigned short ushortT;
typedef unsigned int uintT;
typedef __attribute__((ext_vector_type(8))) __bf16 bf16x8;
typedef __attribute__((ext_vector_type(4))) float f32x4;

#define MFMA16(a, b, c) __builtin_amdgcn_mfma_f32_16x16x32_bf16(a, b, c, 0, 0, 0)

__device__ inline float b2f(ushortT u) {
  return __uint_as_float(((uintT)u) << 16);
}
__device__ inline ushortT f2b(float f) {  // round-to-nearest-even
  uintT x = __float_as_uint(f);
  uintT r = x + 0x7fffu + ((x >> 16) & 1u);
  return (ushortT)(r >> 16);
}

__device__ inline float gelu_tanh(float v) {
  // 0.5*v*(1+tanh(t)) == v * sigmoid(2t)
  float t = 0.7978845608028654f * (v + 0.044715f * v * v * v);
  return v / (1.0f + __expf(-2.0f * t));
}

// ------------------------------------------------------------- dtype detect
// fp32 data read as shorts: even-index = low mantissa half -> random exponent
// field; bf16 weights are all |v| < 1. flag=1 means inputs are fp32.
__global__ __launch_bounds__(256) void detect_dtype(
    const ushortT* __restrict__ w, int* __restrict__ flag) {
  __shared__ int red;
  if (threadIdx.x == 0) red = 0;
  __syncthreads();
  int crazy = 0;
  for (int i = threadIdx.x; i < 4096; i += 256) {
    uintT e = (w[2 * i] >> 7) & 0xFF;
    if (e >= 150) crazy = 1;  // |v| >= 2^23: impossible for real bf16 weights
  }
  if (crazy) atomicOr(&red, 1);
  __syncthreads();
  if (threadIdx.x == 0) *flag = red;
}

// ------------------------------------------------------------- small vectors
struct VecArgs {
  const void* src[8];
  int n[8];
  int dstoff[8];
};
__global__ __launch_bounds__(256) void convert_vecs(
    VecArgs a, ushortT* __restrict__ pv, const int* __restrict__ flag) {
  int fl = *flag;
  int t = blockIdx.y;
  int i = blockIdx.x * 256 + threadIdx.x;
  if (i >= a.n[t]) return;
  float v = fl ? ((const float*)a.src[t])[i] : b2f(((const ushortT*)a.src[t])[i]);
  pv[a.dstoff[t] + i] = f2b(v);
}

// ---------------------------------------------------------------- transpose
// in: [K,N] (flag dtype) -> out: [N,K] bf16. 32x32 LDS tiles.
__global__ __launch_bounds__(256) void transpose_any(
    const void* __restrict__ in, ushortT* __restrict__ out, int K, int N,
    const int* __restrict__ flag) {
  __shared__ ushortT t[32][33];
  int fl = *flag;
  int n0 = blockIdx.x * 32, k0 = blockIdx.y * 32;
  int x = threadIdx.x, y0 = threadIdx.y;
#pragma unroll
  for (int i = y0; i < 32; i += 8) {
    size_t idx = (size_t)(k0 + i) * N + n0 + x;
    t[i][x] = fl ? f2b(((const float*)in)[idx]) : ((const ushortT*)in)[idx];
  }
  __syncthreads();
#pragma unroll
  for (int i = y0; i < 32; i += 8)
    out[(size_t)(n0 + i) * K + k0 + x] = t[x][i];
}

// ---------------------------------------------------------------- layernorm
// MODE 0: input is flag-dtype (external x). MODE 1: input is fp32 (internal).
template <int MODE>
__global__ __launch_bounds__(256) void ln_kernel(
    const void* __restrict__ xin, const ushortT* __restrict__ g,
    const ushortT* __restrict__ bb, ushortT* __restrict__ out,
    const int* __restrict__ flag) {
  const int C = 768;
  bool f32;
  if constexpr (MODE == 1) f32 = true; else f32 = (*flag != 0);
  size_t row = blockIdx.x;
  size_t base = row * C;
  int tid = threadIdx.x;
  const float* xf = (const float*)xin;
  const ushortT* xb = (const ushortT*)xin;
  float v0 = f32 ? xf[base + tid]       : b2f(xb[base + tid]);
  float v1 = f32 ? xf[base + tid + 256] : b2f(xb[base + tid + 256]);
  float v2 = f32 ? xf[base + tid + 512] : b2f(xb[base + tid + 512]);
  float s = v0 + v1 + v2;
  float q = v0 * v0 + v1 * v1 + v2 * v2;
#pragma unroll
  for (int off = 32; off; off >>= 1) {
    s += __shfl_xor(s, off);
    q += __shfl_xor(q, off);
  }
  __shared__ float as_[4], aq_[4];
  if ((tid & 63) == 0) { as_[tid >> 6] = s; aq_[tid >> 6] = q; }
  __syncthreads();
  s = as_[0] + as_[1] + as_[2] + as_[3];
  q = aq_[0] + aq_[1] + aq_[2] + aq_[3];
  float mu = s * (1.0f / 768.0f);
  float var = q * (1.0f / 768.0f) - mu * mu;
  float rs = rsqrtf(var + 1e-5f);
  ushortT* orow = out + base;
  orow[tid]       = f2b((v0 - mu) * rs * b2f(g[tid])       + b2f(bb[tid]));
  orow[tid + 256] = f2b((v1 - mu) * rs * b2f(g[tid + 256]) + b2f(bb[tid + 256]));
  orow[tid + 512] = f2b((v2 - mu) * rs * b2f(g[tid + 512]) + b2f(bb[tid + 512]));
}

// ---------------------------------------------------------------- GEMM
// C[M,N] = A[M,K] @ Bt[N,K]^T + bias. 128x128 tile, BK=32, 4 waves 2x2,
// each wave 4x4 16x16x32 MFMAs. LDS stride 40 shorts.
// EPI: 0 bias->bf16 | 1 bias+gelu->bf16 | 2 bias+res(flag dtype)->fp32
//      3 bias+res(fp32)->flag-dtype out
template <int EPI>
__global__ __launch_bounds__(256) void gemm_bf16(
    const ushortT* __restrict__ A, const ushortT* __restrict__ Bt,
    const ushortT* __restrict__ bias, const void* __restrict__ res,
    void* __restrict__ out, int N, int K, const int* __restrict__ flag) {
  constexpr int LDT = 40;
  __shared__ ushortT As[128 * LDT];
  __shared__ ushortT Bs[128 * LDT];
  int fl = (EPI >= 2) ? *flag : 0;
  int tid = threadIdx.x;
  int lane = tid & 63, wave = tid >> 6;
  int quad = lane >> 4, col = lane & 15;
  int wm = (wave >> 1) << 6, wn = (wave & 1) << 6;
  int m0 = blockIdx.y << 7, n0 = blockIdx.x << 7;

  const ushortT* pa = A + (size_t)(m0 + (tid >> 2)) * K + ((tid & 3) << 3);
  const ushortT* pb = Bt + (size_t)(n0 + (tid >> 2)) * K + ((tid & 3) << 3);
  ushortT* wa = As + (tid >> 2) * LDT + ((tid & 3) << 3);
  ushortT* wb = Bs + (tid >> 2) * LDT + ((tid & 3) << 3);
  size_t rs64 = (size_t)64 * K;

  f32x4 acc[4][4] = {};

  for (int k0 = 0; k0 < K; k0 += 32) {
    uint4 a0 = *(const uint4*)(pa + k0);
    uint4 a1 = *(const uint4*)(pa + rs64 + k0);
    uint4 b0 = *(const uint4*)(pb + k0);
    uint4 b1 = *(const uint4*)(pb + rs64 + k0);
    __syncthreads();
    *(uint4*)wa = a0;
    *(uint4*)(wa + 64 * LDT) = a1;
    *(uint4*)wb = b0;
    *(uint4*)(wb + 64 * LDT) = b1;
    __syncthreads();
    bf16x8 af[4], bfr[4];
#pragma unroll
    for (int mi = 0; mi < 4; ++mi)
      af[mi] = *(const bf16x8*)(As + (wm + mi * 16 + col) * LDT + quad * 8);
#pragma unroll
    for (int ni = 0; ni < 4; ++ni)
      bfr[ni] = *(const bf16x8*)(Bs + (wn + ni * 16 + col) * LDT + quad * 8);
#pragma unroll
    for (int mi = 0; mi < 4; ++mi)
#pragma unroll
      for (int ni = 0; ni < 4; ++ni)
        acc[mi][ni] = MFMA16(af[mi], bfr[ni], acc[mi][ni]);
  }

#pragma unroll
  for (int mi = 0; mi < 4; ++mi) {
#pragma unroll
    for (int ni = 0; ni < 4; ++ni) {
      int gc = n0 + wn + ni * 16 + col;
      float bv = b2f(bias[gc]);
      int gr0 = m0 + wm + mi * 16 + quad * 4;
#pragma unroll
      for (int r = 0; r < 4; ++r) {
        size_t idx = (size_t)(gr0 + r) * N + gc;
        float v = acc[mi][ni][r] + bv;
        if constexpr (EPI == 1) v = gelu_tanh(v);
        if constexpr (EPI == 2) {
          v += fl ? ((const float*)res)[idx] : b2f(((const ushortT*)res)[idx]);
          ((float*)out)[idx] = v;
        } else if constexpr (EPI == 3) {
          v += ((const float*)res)[idx];
          if (fl) ((float*)out)[idx] = v;
          else    ((ushortT*)out)[idx] = f2b(v);
        } else {
          ((ushortT*)out)[idx] = f2b(v);
        }
      }
    }
  }
}

// ---------------------------------------------------------------- attention
// Flash attention, causal. One wave per (b,h,16-row q-tile); 32-key tiles.
__global__ __launch_bounds__(64) void attn_kernel(
    const ushortT* __restrict__ qkv, ushortT* __restrict__ y) {
  const int T = 2048, H = 12, C3 = 2304;
  int b = blockIdx.y / H, h = blockIdx.y % H;
  int q0 = blockIdx.x << 4;
  int lane = threadIdx.x;
  int quad = lane >> 4, n = lane & 15;

  const ushortT* base = qkv + (size_t)b * T * C3;
  const ushortT* qrow = base + (size_t)(q0 + n) * C3 + h * 64 + quad * 8;
  bf16x8 aq0 = *(const bf16x8*)qrow;         // Q[m=n][d=quad*8+j]
  bf16x8 aq1 = *(const bf16x8*)(qrow + 32);  // d+32

  __shared__ ushortT Vs[32 * 72];  // [key][d], stride 72
  __shared__ ushortT Ps[16 * 40];  // [q][key], stride 40

  f32x4 O[4] = {};
  float mrow[4] = {-1e30f, -1e30f, -1e30f, -1e30f};
  float lrow[4] = {};

  const ushortT* kbase = base + 768 + h * 64;
  const ushortT* vbase = base + 1536 + h * 64;
  int vkey = lane & 31, vd = (lane >> 5) << 5;

  int ktiles = (q0 + 47) >> 5;
  for (int kt = 0; kt < ktiles; ++kt) {
    int k0 = kt << 5;
    const ushortT* kp = kbase + (size_t)(k0 + n) * C3 + quad * 8;
    bf16x8 bk00 = *(const bf16x8*)kp;
    bf16x8 bk01 = *(const bf16x8*)(kp + 32);
    bf16x8 bk10 = *(const bf16x8*)(kp + (size_t)16 * C3);
    bf16x8 bk11 = *(const bf16x8*)(kp + (size_t)16 * C3 + 32);
    const uint4* vp = (const uint4*)(vbase + (size_t)(k0 + vkey) * C3 + vd);
    uint4 vv0 = vp[0], vv1 = vp[1], vv2 = vp[2], vv3 = vp[3];

    __syncthreads();
    uint4* vw = (uint4*)(Vs + vkey * 72 + vd);
    vw[0] = vv0; vw[1] = vv1; vw[2] = vv2; vw[3] = vv3;

    f32x4 S0 = {}, S1 = {};
    S0 = MFMA16(aq0, bk00, S0);
    S0 = MFMA16(aq1, bk01, S0);
    S1 = MFMA16(aq0, bk10, S1);
    S1 = MFMA16(aq1, bk11, S1);

#pragma unroll
    for (int r = 0; r < 4; ++r) {
      int qg = q0 + quad * 4 + r;
      float s0 = (k0 + n <= qg) ? S0[r] * 0.125f : -1e30f;
      float s1 = (k0 + 16 + n <= qg) ? S1[r] * 0.125f : -1e30f;
      float lm = fmaxf(s0, s1);
#pragma unroll
      for (int off = 8; off; off >>= 1) lm = fmaxf(lm, __shfl_xor(lm, off));
      float mn = fmaxf(mrow[r], lm);
      float alpha = __expf(mrow[r] - mn);
      float p0 = __expf(s0 - mn);
      float p1 = __expf(s1 - mn);
      float ls = p0 + p1;
#pragma unroll
      for (int off = 8; off; off >>= 1) ls += __shfl_xor(ls, off);
      lrow[r] = lrow[r] * alpha + ls;
      mrow[r] = mn;
      O[0][r] *= alpha; O[1][r] *= alpha; O[2][r] *= alpha; O[3][r] *= alpha;
      Ps[(quad * 4 + r) * 40 + n] = f2b(p0);
      Ps[(quad * 4 + r) * 40 + 16 + n] = f2b(p1);
    }
    __syncthreads();
    bf16x8 pa = *(const bf16x8*)(Ps + n * 40 + quad * 8);
#pragma unroll
    for (int dt = 0; dt < 4; ++dt) {
      union { ushortT u[8]; bf16x8 v; } vb;
#pragma unroll
      for (int j = 0; j < 8; ++j) vb.u[j] = Vs[(quad * 8 + j) * 72 + dt * 16 + n];
      O[dt] = MFMA16(pa, vb.v, O[dt]);
    }
  }

#pragma unroll
  for (int dt = 0; dt < 4; ++dt) {
#pragma unroll
    for (int r = 0; r < 4; ++r) {
      int qg = q0 + quad * 4 + r;
      float v = O[dt][r] / lrow[r];
      y[(size_t)(b * T + qg) * 768 + h * 64 + dt * 16 + n] = f2b(v);
    }
  }
}

// ---------------------------------------------------------------- launch
extern "C" void kernel_launch(void* const* d_in, const int* in_sizes, int n_in,
                              void* d_out, int out_size, void* d_ws,
                              size_t ws_size, hipStream_t stream) {
  (void)in_sizes; (void)n_in; (void)out_size; (void)ws_size;
  const void* x       = d_in[0];
  const void* w_attn  = d_in[3];
  const void* w_aproj = d_in[5];
  const void* w_fc    = d_in[9];
  const void* w_mproj = d_in[11];

  char* ws = (char*)d_ws;
  ushortT* h1  = (ushortT*)(ws);                 // [8192,768]  bf16
  ushortT* qkv = (ushortT*)(ws + 12582912);      // [8192,2304] bf16
  ushortT* yb  = (ushortT*)(ws + 50331648);      // [8192,768]  bf16
  float*   x1  = (float*)(ws + 62914560);        // [8192,768]  fp32
  ushortT* fcg = (ushortT*)(ws + 88080384);      // [8192,3072] bf16
  ushortT* wT0 = (ushortT*)(ws + 138412032);     // w_attn^T  [2304,768]
  ushortT* wT1 = (ushortT*)(ws + 141950976);     // w_aproj^T [768,768]
  ushortT* wT2 = (ushortT*)(ws + 143130624);     // w_fc^T    [3072,768]
  ushortT* wT3 = (ushortT*)(ws + 147849216);     // w_mproj^T [768,3072]
  ushortT* pv  = (ushortT*)(ws + 152567808);     // packed vectors (bf16)
  int*     flag = (int*)(ws + 152600576);
  ushortT* h2  = h1;  // h1 dead after qkv GEMM

  // packed vector offsets
  const int O_LN1G = 0, O_LN1B = 768, O_BATT = 1536, O_BAPR = 3840,
            O_LN2G = 4608, O_LN2B = 5376, O_BFC = 6144, O_BMPR = 9216;

  detect_dtype<<<1, 256, 0, stream>>>((const ushortT*)w_fc, flag);

  VecArgs va;
  va.src[0] = d_in[1];  va.n[0] = 768;  va.dstoff[0] = O_LN1G;
  va.src[1] = d_in[2];  va.n[1] = 768;  va.dstoff[1] = O_LN1B;
  va.src[2] = d_in[4];  va.n[2] = 2304; va.dstoff[2] = O_BATT;
  va.src[3] = d_in[6];  va.n[3] = 768;  va.dstoff[3] = O_BAPR;
  va.src[4] = d_in[7];  va.n[4] = 768;  va.dstoff[4] = O_LN2G;
  va.src[5] = d_in[8];  va.n[5] = 768;  va.dstoff[5] = O_LN2B;
  va.src[6] = d_in[10]; va.n[6] = 3072; va.dstoff[6] = O_BFC;
  va.src[7] = d_in[12]; va.n[7] = 768;  va.dstoff[7] = O_BMPR;
  convert_vecs<<<dim3(12, 8), 256, 0, stream>>>(va, pv, flag);

  dim3 tb(32, 8);
  transpose_any<<<dim3(72, 24), tb, 0, stream>>>(w_attn, wT0, 768, 2304, flag);
  transpose_any<<<dim3(24, 24), tb, 0, stream>>>(w_aproj, wT1, 768, 768, flag);
  transpose_any<<<dim3(96, 24), tb, 0, stream>>>(w_fc, wT2, 768, 3072, flag);
  transpose_any<<<dim3(24, 96), tb, 0, stream>>>(w_mproj, wT3, 3072, 768, flag);

  ln_kernel<0><<<8192, 256, 0, stream>>>(x, pv + O_LN1G, pv + O_LN1B, h1, flag);
  gemm_bf16<0><<<dim3(18, 64), 256, 0, stream>>>(h1, wT0, pv + O_BATT, nullptr,
                                                 qkv, 2304, 768, flag);
  attn_kernel<<<dim3(128, 48), 64, 0, stream>>>(qkv, yb);
  gemm_bf16<2><<<dim3(6, 64), 256, 0, stream>>>(yb, wT1, pv + O_BAPR, x, x1,
                                                768, 768, flag);
  ln_kernel<1><<<8192, 256, 0, stream>>>(x1, pv + O_LN2G, pv + O_LN2B, h2, flag);
  gemm_bf16<1><<<dim3(24, 64), 256, 0, stream>>>(h2, wT2, pv + O_BFC, nullptr,
                                                 fcg, 3072, 768, flag);
  gemm_bf16<3><<<dim3(6, 64), 256, 0, stream>>>(fcg, wT3, pv + O_BMPR, x1,
                                                d_out, 768, 3072, flag);
}